// Round 2
// baseline (248.090 us; speedup 1.0000x reference)
//
#include <hip/hip_runtime.h>
#include <hip/hip_bf16.h>

// GraphSAGE 2-layer forward, MI355X. R14 = R13 (L2-resident channel-split
// gathers: xq[4][N][32] bf16 slices, hp2[2][N][64] fp8 slices) but with
// pre restored to fp32 (R13's bf16 pre pushed absmax 0.7% over threshold).

#define N_NODES 50000
#define IN_C    128
#define HID_C   256
#define OUT_C   128
#define N_EDGES 600000

// prep block partition: count first (latency-bound), then streaming
#define PB_CNT  2344                 // ceil(600000/256)
#define PB_W1   (PB_CNT + 256)       // 2600
#define PB_W2   (PB_W1 + 256)        // 2856
#define PB_X    (PB_W2 + 6250)       // 9106 total

typedef __attribute__((ext_vector_type(8))) short short8;   // 8 bf16 (16B)
typedef __attribute__((ext_vector_type(4))) float f32x4;
typedef __attribute__((ext_vector_type(2))) float f32x2;

__device__ __forceinline__ float bflo(unsigned u) {
    union { unsigned x; float f; } c; c.x = u << 16; return c.f;
}
__device__ __forceinline__ float bfhi(unsigned u) {
    union { unsigned x; float f; } c; c.x = u & 0xffff0000u; return c.f;
}
__device__ __forceinline__ unsigned f2fp8(float v) {
    return (unsigned)__builtin_amdgcn_cvt_pk_fp8_f32(v, v, 0, false) & 0xffu;
}
// accumulate 4 fp8 bytes (one u32) into a[0..3]
__device__ __forceinline__ void acc_fp8x4(float* a, unsigned u) {
    f32x2 lo = __builtin_amdgcn_cvt_pk_f32_fp8(u, false);
    f32x2 hi = __builtin_amdgcn_cvt_pk_f32_fp8(u, true);
    a[0] += lo[0]; a[1] += lo[1]; a[2] += hi[0]; a[3] += hi[1];
}

// ---------------- fused prep (+ degree count) ----------------
// x -> xq[4][N][32] bf16 (channel-blocked: chunk c>>5, pos c&31)
__global__ __launch_bounds__(256) void prep(
    const float* __restrict__ x, __hip_bfloat16* __restrict__ xq,
    const float* __restrict__ W1l, const float* __restrict__ W1r,
    const float* __restrict__ W2l, const float* __restrict__ W2r,
    __hip_bfloat16* __restrict__ W1t, __hip_bfloat16* __restrict__ W2t,
    const int* __restrict__ dstI, int* __restrict__ cnt) {
    int b = blockIdx.x;
    if (b < PB_CNT) {
        int e = b * 256 + threadIdx.x;
        if (e < N_EDGES) atomicAdd(&cnt[dstI[e]], 1);
    } else if (b < PB_W1) {
        int reg = b - PB_CNT;
        int half = reg >> 7;
        int t = (reg & 127) * 256 + threadIdx.x;
        int k = t >> 8, n = t & 255;
        const float* src = half ? W1r : W1l;
        W1t[n * 256 + half * 128 + k] = __float2bfloat16(src[t]);
    } else if (b < PB_W2) {
        int reg = b - PB_W1;
        int half = reg >> 7;
        int t = (reg & 127) * 256 + threadIdx.x;
        int k = t >> 7, n = t & 127;
        const float* src = half ? W2r : W2l;
        W2t[(size_t)(half * 128 + n) * 256 + k] = __float2bfloat16(src[t]);
    } else {
        int t = (b - PB_W2) * 256 + threadIdx.x;
        if (t >= N_NODES * 32) return;
        int row = t >> 5, c = (t & 31) * 4;
        float4 v = *(const float4*)(x + (size_t)row * 128 + c);
        __hip_bfloat16* d = xq + (size_t)(c >> 5) * (N_NODES * 32)
                               + (size_t)row * 32 + (c & 31);
        __hip_bfloat162 p0, p1;
        p0.x = __float2bfloat16(v.x); p0.y = __float2bfloat16(v.y);
        p1.x = __float2bfloat16(v.z); p1.y = __float2bfloat16(v.w);
        *(__hip_bfloat162*)d = p0;
        *(__hip_bfloat162*)(d + 2) = p1;
    }
}

// ---------------- CSR build ----------------
__global__ __launch_bounds__(256) void assign_offsets(
    const int* __restrict__ cnt, int* __restrict__ row_ptr,
    int* __restrict__ cursor, int* __restrict__ total, int n) {
    __shared__ int tmp[256];
    __shared__ int sbase;
    int t = threadIdx.x, g = blockIdx.x * 256 + t;
    int v = (g < n) ? cnt[g] : 0;
    tmp[t] = v; __syncthreads();
    for (int off = 1; off < 256; off <<= 1) {
        int u = (t >= off) ? tmp[t - off] : 0;
        __syncthreads();
        tmp[t] += u;
        __syncthreads();
    }
    if (t == 255) sbase = atomicAdd(total, tmp[255]);
    __syncthreads();
    if (g < n) {
        int e = sbase + tmp[t] - v;
        row_ptr[g] = e;
        cursor[g] = e;
    }
}

__global__ void fill_csr(const int* __restrict__ srcI, const int* __restrict__ dstI,
                         int* __restrict__ cursor, int* __restrict__ col, int E) {
    int e = blockIdx.x * blockDim.x + threadIdx.x;
    if (e < E) {
        int pos = atomicAdd(&cursor[dstI[e]], 1);
        col[pos] = srcI[e];
    }
}

// ---------------- layer-1 mean aggregation: 4 channel-split passes ----------------
// pass p (blockIdx.y) gathers 64B/edge from xq slice p (3.2MB, L2-resident).
// Writes A1[node][128] (agg only), cols p*32..p*32+31.
__global__ __launch_bounds__(256) void aggregate_l1(
    const __hip_bfloat16* __restrict__ xq,
    const int* __restrict__ row_ptr, const int* __restrict__ deg,
    const int* __restrict__ col,
    __hip_bfloat16* __restrict__ A1) {
    int p = blockIdx.y;
    int node = blockIdx.x * 16 + (threadIdx.x >> 4);
    int sl   = threadIdx.x & 15;
    if (node >= N_NODES) return;
    int beg = row_ptr[node];
    int d   = deg[node];
    const __hip_bfloat16* tab = xq + (size_t)p * (N_NODES * 32) + sl * 2;
    float a0 = 0.f, a1 = 0.f;

    unsigned v0, v1, v2, v3;
    int j = 0;
    if (d >= 4) {
        int s0 = col[beg + 0], s1 = col[beg + 1];
        int s2 = col[beg + 2], s3 = col[beg + 3];
        v0 = *(const unsigned*)(tab + (size_t)s0 * 32);
        v1 = *(const unsigned*)(tab + (size_t)s1 * 32);
        v2 = *(const unsigned*)(tab + (size_t)s2 * 32);
        v3 = *(const unsigned*)(tab + (size_t)s3 * 32);
        for (; j + 8 <= d; j += 4) {
            int t0 = col[beg + j + 4], t1 = col[beg + j + 5];
            int t2 = col[beg + j + 6], t3 = col[beg + j + 7];
            unsigned w0 = *(const unsigned*)(tab + (size_t)t0 * 32);
            unsigned w1 = *(const unsigned*)(tab + (size_t)t1 * 32);
            unsigned w2 = *(const unsigned*)(tab + (size_t)t2 * 32);
            unsigned w3 = *(const unsigned*)(tab + (size_t)t3 * 32);
            a0 += (bflo(v0) + bflo(v1)) + (bflo(v2) + bflo(v3));
            a1 += (bfhi(v0) + bfhi(v1)) + (bfhi(v2) + bfhi(v3));
            v0 = w0; v1 = w1; v2 = w2; v3 = w3;
        }
        a0 += (bflo(v0) + bflo(v1)) + (bflo(v2) + bflo(v3));
        a1 += (bfhi(v0) + bfhi(v1)) + (bfhi(v2) + bfhi(v3));
        j += 4;
    }
    int rem = d - j;
    if (rem > 0) {
        int s0 = col[beg + j];
        int s1 = (rem > 1) ? col[beg + j + 1] : s0;
        int s2 = (rem > 2) ? col[beg + j + 2] : s0;
        unsigned t0 = *(const unsigned*)(tab + (size_t)s0 * 32);
        unsigned t1 = *(const unsigned*)(tab + (size_t)s1 * 32);
        unsigned t2 = *(const unsigned*)(tab + (size_t)s2 * 32);
        a0 += bflo(t0); a1 += bfhi(t0);
        if (rem > 1) { a0 += bflo(t1); a1 += bfhi(t1); }
        if (rem > 2) { a0 += bflo(t2); a1 += bfhi(t2); }
    }

    float inv = 1.f / (float)max(d, 1);
    __hip_bfloat162 o;
    o.x = __float2bfloat16(a0 * inv);
    o.y = __float2bfloat16(a1 * inv);
    *(__hip_bfloat162*)(A1 + (size_t)node * 128 + p * 32 + sl * 2) = o;
}

// ---------------- final aggregation: 2 channel-split fp8 passes ----------------
// pass p gathers 64B/edge from hp2 slice p (3.2MB fp8, L2-resident);
// out = mean + pre(fp32).
__global__ __launch_bounds__(256) void aggregate_final(
    const unsigned char* __restrict__ hp2,    // [2][N][64] fp8 e4m3
    const int* __restrict__ row_ptr, const int* __restrict__ deg,
    const int* __restrict__ col,
    const float* __restrict__ pre,            // [N][128] fp32
    float* __restrict__ outp) {
    int p = blockIdx.y;
    int node = blockIdx.x * 16 + (threadIdx.x >> 4);
    int sl   = threadIdx.x & 15;
    if (node >= N_NODES) return;
    int beg = row_ptr[node];
    int d   = deg[node];
    const unsigned char* tab = hp2 + (size_t)p * (N_NODES * 64) + sl * 4;
    float a[4];
    #pragma unroll
    for (int c = 0; c < 4; ++c) a[c] = 0.f;

    unsigned v0, v1, v2, v3;
    int j = 0;
    if (d >= 4) {
        int s0 = col[beg + 0], s1 = col[beg + 1];
        int s2 = col[beg + 2], s3 = col[beg + 3];
        v0 = *(const unsigned*)(tab + (size_t)s0 * 64);
        v1 = *(const unsigned*)(tab + (size_t)s1 * 64);
        v2 = *(const unsigned*)(tab + (size_t)s2 * 64);
        v3 = *(const unsigned*)(tab + (size_t)s3 * 64);
        for (; j + 8 <= d; j += 4) {
            int t0 = col[beg + j + 4], t1 = col[beg + j + 5];
            int t2 = col[beg + j + 6], t3 = col[beg + j + 7];
            unsigned w0 = *(const unsigned*)(tab + (size_t)t0 * 64);
            unsigned w1 = *(const unsigned*)(tab + (size_t)t1 * 64);
            unsigned w2 = *(const unsigned*)(tab + (size_t)t2 * 64);
            unsigned w3 = *(const unsigned*)(tab + (size_t)t3 * 64);
            acc_fp8x4(a, v0); acc_fp8x4(a, v1);
            acc_fp8x4(a, v2); acc_fp8x4(a, v3);
            v0 = w0; v1 = w1; v2 = w2; v3 = w3;
        }
        acc_fp8x4(a, v0); acc_fp8x4(a, v1);
        acc_fp8x4(a, v2); acc_fp8x4(a, v3);
        j += 4;
    }
    for (; j < d; ++j) {
        unsigned v = *(const unsigned*)(tab + (size_t)col[beg + j] * 64);
        acc_fp8x4(a, v);
    }

    float inv = 1.f / (float)max(d, 1);
    const float* pp = pre + (size_t)node * 128 + p * 64 + sl * 4;
    float4 p0 = *(const float4*)pp;
    *(float4*)(outp + (size_t)node * 128 + p * 64 + sl * 4) =
        make_float4(a[0] * inv + p0.x, a[1] * inv + p0.y,
                    a[2] * inv + p0.z, a[3] * inv + p0.w);
}

// ---------------- layer-1 bf16 MFMA GEMM (128x128 tile) ----------------
// A operand: K 0..127 from A1[N][128] (agg), K 128..255 from xq chunks.
// outBf = relu(A@Bt^T + bias), row stride 256 bf16; LDS-repacked epilogue.

#define GBM 128
#define GBN 128
#define GBK 64
#define EP_STRIDE_BF 132     // bf16 elems: 264 B stride, 2-way max conflict

__device__ __forceinline__ void gload16(const void* g, void* l) {
    typedef const __attribute__((address_space(1))) unsigned int* gp_t;
    typedef __attribute__((address_space(3))) unsigned int* lp_t;
    __builtin_amdgcn_global_load_lds((gp_t)g, (lp_t)l, 16, 0, 0);
}

__global__ __launch_bounds__(256) void gemm_mfma(
    const __hip_bfloat16* __restrict__ A1,   // [N][128] agg half (K 0..127)
    const __hip_bfloat16* __restrict__ xq,   // [4][N][32]  (K 128..255)
    const __hip_bfloat16* __restrict__ Bt,
    const float* __restrict__ bias,
    __hip_bfloat16* __restrict__ outBf,
    int M) {
    __shared__ char sm[GBM * EP_STRIDE_BF * 2];     // 33 KB; staging uses first 32 KB
    __hip_bfloat16* Als = (__hip_bfloat16*)sm;
    __hip_bfloat16* Bls = (__hip_bfloat16*)(sm + GBM * GBK * 2);

    int tid  = threadIdx.x;
    int wave = tid >> 6, lane = tid & 63;
    int wm = wave >> 1, wn = wave & 1;
    int mb = blockIdx.x * GBM, nb = blockIdx.y * GBN;

    int srow_base = wave * 32;
    int lrow = lane >> 3;
    int pch  = lane & 7;

    f32x4 acc[4][4];
    #pragma unroll
    for (int i = 0; i < 4; ++i)
        #pragma unroll
        for (int j = 0; j < 4; ++j)
            acc[i][j] = (f32x4){0.f, 0.f, 0.f, 0.f};

    for (int kt = 0; kt < 256; kt += GBK) {
        #pragma unroll
        for (int t = 0; t < 4; ++t) {
            int rloc = srow_base + t * 8 + lrow;
            int lch  = pch ^ (rloc & 7);
            int ga_row = mb + rloc; if (ga_row >= M) ga_row = M - 1;
            const __hip_bfloat16* ga;
            if (kt < 128) {
                ga = A1 + (size_t)ga_row * 128 + kt + lch * 8;
            } else {
                int chunk = ((kt - 128) >> 5) + (lch >> 2);
                ga = xq + (size_t)chunk * (N_NODES * 32)
                        + (size_t)ga_row * 32 + (lch & 3) * 8;
            }
            gload16(ga, &Als[(srow_base + t * 8) * GBK]);
            const __hip_bfloat16* gb = Bt + (size_t)(nb + rloc) * 256 + kt + lch * 8;
            gload16(gb, &Bls[(srow_base + t * 8) * GBK]);
        }
        __syncthreads();

        #pragma unroll
        for (int ks = 0; ks < GBK; ks += 32) {
            int chunkL = (ks >> 3) + (lane >> 4);
            short8 af[4], bf[4];
            #pragma unroll
            for (int i = 0; i < 4; ++i) {
                int row = wm * 64 + i * 16 + (lane & 15);
                int pc  = chunkL ^ (row & 7);
                af[i] = *(const short8*)&Als[row * GBK + pc * 8];
            }
            #pragma unroll
            for (int j = 0; j < 4; ++j) {
                int row = wn * 64 + j * 16 + (lane & 15);
                int pc  = chunkL ^ (row & 7);
                bf[j] = *(const short8*)&Bls[row * GBK + pc * 8];
            }
            #pragma unroll
            for (int i = 0; i < 4; ++i)
                #pragma unroll
                for (int j = 0; j < 4; ++j)
                    acc[i][j] = __builtin_amdgcn_mfma_f32_16x16x32_bf16(
                        af[i], bf[j], acc[i][j], 0, 0, 0);
        }
        __syncthreads();
    }

    // epilogue: C/D layout col=lane&15, row=(lane>>4)*4+reg
    int cn[4];
    float bc[4];
    __hip_bfloat16* sb = (__hip_bfloat16*)sm;
    #pragma unroll
    for (int j = 0; j < 4; ++j) {
        cn[j] = wn * 64 + j * 16 + (lane & 15);
        bc[j] = bias[nb + cn[j]];
    }
    #pragma unroll
    for (int i = 0; i < 4; ++i)
        #pragma unroll
        for (int r = 0; r < 4; ++r) {
            int lr = wm * 64 + i * 16 + (lane >> 4) * 4 + r;
            #pragma unroll
            for (int j = 0; j < 4; ++j)
                sb[lr * EP_STRIDE_BF + cn[j]] =
                    __float2bfloat16(fmaxf(acc[i][j][r] + bc[j], 0.f));
        }
    __syncthreads();
    #pragma unroll
    for (int it = 0; it < 8; ++it) {
        int chunk = it * 256 + tid;          // 0..2047, 16B each
        int lr  = chunk >> 4;                // 16 chunks per 256B data row
        int lcB = (chunk & 15) * 16;
        int grow = mb + lr;
        if (grow < M)
            *(float4*)((char*)outBf + (size_t)grow * 512 + nb * 2 + lcB) =
                *(const float4*)((const char*)sb + lr * (EP_STRIDE_BF * 2) + lcB);
    }
}

// ---------------- layer-2 fused GEMM: single pass, dual output ----------------
// A = h [M][256]; Bt = W2t [256][256] (rows 0..127 -> hp fp8, 128..255 -> pre).
// Wave 0/1 -> hp2 slices 0/1 (channel-blocked fp8); waves 2/3 -> pre fp32 + b2.
#define GBM2 64

__global__ __launch_bounds__(256) void gemm2_fused(
    const __hip_bfloat16* __restrict__ A,
    const __hip_bfloat16* __restrict__ Bt,
    const float* __restrict__ b2,
    unsigned char* __restrict__ outF8,       // hp2 [2][N][64] fp8
    float* __restrict__ pre,                 // pre [N][128] fp32
    int M) {
    __shared__ __hip_bfloat16 Als[GBM2 * GBK];   // 8 KB
    __shared__ __hip_bfloat16 Bls[256 * GBK];    // 32 KB

    int tid  = threadIdx.x;
    int wave = tid >> 6, lane = tid & 63;
    int mb = blockIdx.x * GBM2;
    int lrow = lane >> 3;
    int pch  = lane & 7;

    f32x4 acc[4][4];
    #pragma unroll
    for (int i = 0; i < 4; ++i)
        #pragma unroll
        for (int j = 0; j < 4; ++j)
            acc[i][j] = (f32x4){0.f, 0.f, 0.f, 0.f};

    for (int kt = 0; kt < 256; kt += GBK) {
        #pragma unroll
        for (int t = 0; t < 2; ++t) {
            int g = wave * 2 + t;
            int rloc = g * 8 + lrow;                 // 0..63
            int lch  = pch ^ (rloc & 7);
            int ga_row = mb + rloc; if (ga_row >= M) ga_row = M - 1;
            gload16(A + (size_t)ga_row * 256 + kt + lch * 8, &Als[g * 8 * GBK]);
        }
        #pragma unroll
        for (int t = 0; t < 8; ++t) {
            int g = wave * 8 + t;
            int rloc = g * 8 + lrow;                 // 0..255
            int lch  = pch ^ (rloc & 7);
            gload16(Bt + (size_t)rloc * 256 + kt + lch * 8, &Bls[g * 8 * GBK]);
        }
        __syncthreads();

        #pragma unroll
        for (int ks = 0; ks < GBK; ks += 32) {
            int chunkL = (ks >> 3) + (lane >> 4);
            short8 af[4], bf[4];
            #pragma unroll
            for (int i = 0; i < 4; ++i) {
                int row = i * 16 + (lane & 15);          // 0..63
                int pc  = chunkL ^ (row & 7);
                af[i] = *(const short8*)&Als[row * GBK + pc * 8];
            }
            #pragma unroll
            for (int j = 0; j < 4; ++j) {
                int row = wave * 64 + j * 16 + (lane & 15);  // output col
                int pc  = chunkL ^ (row & 7);
                bf[j] = *(const short8*)&Bls[row * GBK + pc * 8];
            }
            #pragma unroll
            for (int i = 0; i < 4; ++i)
                #pragma unroll
                for (int j = 0; j < 4; ++j)
                    acc[i][j] = __builtin_amdgcn_mfma_f32_16x16x32_bf16(
                        af[i], bf[j], acc[i][j], 0, 0, 0);
        }
        __syncthreads();
    }

    // epilogue: col=lane&15 (+j*16+wave*64), row=(lane>>4)*4+reg (+i*16)
    if (wave < 2) {
        // cols 0..127 -> hp2 slice `wave` (channel-blocked fp8)
        unsigned char* hb = outF8 + (size_t)wave * (N_NODES * 64);
        #pragma unroll
        for (int i = 0; i < 4; ++i)
            #pragma unroll
            for (int r = 0; r < 4; ++r) {
                int row = mb + i * 16 + (lane >> 4) * 4 + r;
                if (row >= M) continue;
                #pragma unroll
                for (int j = 0; j < 4; ++j)
                    hb[(size_t)row * 64 + j * 16 + (lane & 15)] =
                        (unsigned char)f2fp8(acc[i][j][r]);
            }
    } else {
        // cols 128..255 -> pre = acc + b2 (fp32)
        int cbase = (wave - 2) * 64;
        float bc[4];
        #pragma unroll
        for (int j = 0; j < 4; ++j) bc[j] = b2[cbase + j * 16 + (lane & 15)];
        #pragma unroll
        for (int i = 0; i < 4; ++i)
            #pragma unroll
            for (int r = 0; r < 4; ++r) {
                int row = mb + i * 16 + (lane >> 4) * 4 + r;
                if (row >= M) continue;
                #pragma unroll
                for (int j = 0; j < 4; ++j)
                    pre[(size_t)row * 128 + cbase + j * 16 + (lane & 15)] =
                        acc[i][j][r] + bc[j];
            }
    }
}

extern "C" void kernel_launch(void* const* d_in, const int* in_sizes, int n_in,
                              void* d_out, int out_size, void* d_ws, size_t ws_size,
                              hipStream_t stream) {
    const float* x    = (const float*)d_in[0];
    const int*   ei   = (const int*)d_in[1];
    const float* W1l  = (const float*)d_in[2];
    const float* b1   = (const float*)d_in[3];
    const float* W1r  = (const float*)d_in[4];
    const float* W2l  = (const float*)d_in[5];
    const float* b2   = (const float*)d_in[6];
    const float* W2r  = (const float*)d_in[7];
    float* out = (float*)d_out;

    const int E = N_EDGES;
    const int N = N_NODES;
    const int* srcI = ei;
    const int* dstI = ei + E;

    // workspace layout (bytes)
    char* w = (char*)d_ws;
    int*            cnt     = (int*)(w + 0);                   // 200000
    int*            total   = (int*)(w + 200000);              // 4 (memset with cnt)
    int*            row_ptr = (int*)(w + 204800);              // 200000
    int*            col     = (int*)(w + 409600);              // 2400000
    __hip_bfloat16* W1t     = (__hip_bfloat16*)(w + 2818048);  // [256][256]
    __hip_bfloat16* W2t     = (__hip_bfloat16*)(w + 2949120);  // [256][256]
    int*            cursor  = (int*)(w + 3080192);             // 200000
    __hip_bfloat16* A1      = (__hip_bfloat16*)(w + 3280896);  // [50000][128] agg
    __hip_bfloat16* xq      = (__hip_bfloat16*)(w + 16080896); // [4][50000][32]
    __hip_bfloat16* h_bf    = (__hip_bfloat16*)(w + 28880896); // [50000][256]
    unsigned char*  hp2     = (unsigned char*)(w + 54480896);  // [2][50000][64] fp8
    float*          pre     = (float*)(w + 60880896);          // [50000][128] fp32

    // ---- zero cnt+total, then fused prep (+degree count) ----
    hipMemsetAsync(cnt, 0, 200004, stream);
    prep<<<PB_X, 256, 0, stream>>>(x, xq, W1l, W1r, W2l, W2r, W1t, W2t, dstI, cnt);

    // ---- CSR build ----
    assign_offsets<<<(N + 255) / 256, 256, 0, stream>>>(cnt, row_ptr, cursor, total, N);
    fill_csr<<<(E + 255) / 256, 256, 0, stream>>>(srcI, dstI, cursor, col, E);

    // ---- layer 1: 4 L2-resident gather passes, then GEMM ----
    aggregate_l1<<<dim3((N + 15) / 16, 4), 256, 0, stream>>>(
        xq, row_ptr, cnt, col, A1);
    {
        dim3 grid((N + GBM - 1) / GBM, HID_C / GBN);
        gemm_mfma<<<grid, 256, 0, stream>>>(A1, xq, W1t, b1, h_bf, N);
    }

    // ---- layer 2: single-pass dual output (h staged once) ----
    gemm2_fused<<<(N + GBM2 - 1) / GBM2, 256, 0, stream>>>(
        h_bf, W2t, b2, hp2, pre, N);

    // ---- final: out = pre + mean(hp), 2 L2-resident fp8 passes ----
    aggregate_final<<<dim3((N + 15) / 16, 2), 256, 0, stream>>>(
        hp2, row_ptr, cnt, col, pre, out);
}